// Round 11
// baseline (10841.982 us; speedup 1.0000x reference)
//
#include <hip/hip_runtime.h>
#include <hip/hip_bf16.h>
#include <hip/hip_fp16.h>

#define S_ 1024
#define B_ 64
#define E_ 512
#define H_ 512
#define G3_ 1536
#define V_ 32000

typedef __hip_bfloat16 bf16;
typedef __half f16;
typedef unsigned long long ULL;

typedef _Float16 half8 __attribute__((ext_vector_type(8)));
typedef float f32x4v __attribute__((ext_vector_type(4)));

// ---------- dtype helpers ----------
template<typename T> struct alignas(4*sizeof(T)) V4 { T v[4]; };

__device__ __forceinline__ float toF(float x){ return x; }
__device__ __forceinline__ float toF(bf16 x){ return __bfloat162float(x); }
__device__ __forceinline__ float toF(f16 x){ return __half2float(x); }
__device__ __forceinline__ void storeF(float* p, float v){ *p = v; }
__device__ __forceinline__ void storeF(bf16* p, float v){ *p = __float2bfloat16(v); }
__device__ __forceinline__ void storeF(f16* p, float v){ *p = __float2half(v); }

__device__ __forceinline__ ULL cohLoad8(const ULL* p){
  return __hip_atomic_load(p, __ATOMIC_RELAXED, __HIP_MEMORY_SCOPE_AGENT);
}
__device__ __forceinline__ void cohStore4(float* p, float v){
  __hip_atomic_store(p, v, __ATOMIC_RELAXED, __HIP_MEMORY_SCOPE_AGENT);
}
__device__ __forceinline__ unsigned flagLoad(const unsigned* p){
  return __hip_atomic_load(p, __ATOMIC_RELAXED, __HIP_MEMORY_SCOPE_AGENT);
}
__device__ __forceinline__ void flagStore(unsigned* p, unsigned v){
  __hip_atomic_store(p, v, __ATOMIC_RELAXED, __HIP_MEMORY_SCOPE_AGENT);
}

// ------------------------------ signal kernel -------------------------------
__global__ __launch_bounds__(256)
void signal_kernel(float* __restrict__ out, long n, float v)
{
  long i = (long)blockIdx.x * 256 + threadIdx.x;
  const long stride = (long)gridDim.x * 256;
  for (; i < n; i += stride) out[i] = v;
}

// ---------------------------- fp32 -> fp16 convert --------------------------
__global__ __launch_bounds__(256)
void convF2H(const float* __restrict__ in, f16* __restrict__ out, long n)
{
  long i = ((long)blockIdx.x * 256 + threadIdx.x) * 8;
  const long stride = (long)gridDim.x * 256 * 8;
  for (; i < n; i += stride) {
    float4 a = *(const float4*)(in + i);
    float4 b = *(const float4*)(in + i + 4);
    half8 o;
    o[0] = (_Float16)a.x; o[1] = (_Float16)a.y; o[2] = (_Float16)a.z; o[3] = (_Float16)a.w;
    o[4] = (_Float16)b.x; o[5] = (_Float16)b.y; o[6] = (_Float16)b.z; o[7] = (_Float16)b.w;
    *(half8*)((_Float16*)out + i) = o;
  }
}

// ------------------------- MFMA fp16 GEMM (no LDS) ---------------------------
// C[m][n] = sum_k A[m][k] * W[n][k], A/W fp16, fp32 accumulate.
// Block 128x128, 4 waves (2x2), wave tile 64x64 = 4x4 MFMA 16x16x32 tiles.
// A/B fragments: lane l loads 8 contiguous fp16 at k = k0 + (l>>4)*8 from
// row (l&15) of its sub-tile. Same per-lane k-slot bijection for A and B =>
// layout-correct independent of the HW k-group map. C/D: col=l&15,
// row=(l>>4)*4+reg [HW-verified].
// GMODE 0: A row = emb16[src[m]] * (src!=0)    (gather, K=512)
// GMODE 1: A[m][k] = k<512 ? Af[m*rsF+k] : Ab[m*rsB+k-512]
// EPI 0: store f16 to Cx (row stride N). EPI 1: f32 tanh(acc+bias[n]) to Cf.
template<int GMODE, int EPI>
__global__ __launch_bounds__(256)
void gemm16(const int* __restrict__ src, const f16* __restrict__ embh,
            const f16* __restrict__ Af, int rsF,
            const f16* __restrict__ Ab, int rsB,
            const f16* __restrict__ Wh,
            f16* __restrict__ Cx, float* __restrict__ Cf,
            const float* __restrict__ bias, int N, int K)
{
  __shared__ int s_tok[128];
  const int tid = threadIdx.x;
  const int m0 = blockIdx.x * 128;
  const int n0 = blockIdx.y * 128;
  const int wid = tid >> 6, lane = tid & 63;
  const int wr = wid >> 1, wc = wid & 1;
  const int lr = lane & 15, lg = lane >> 4;

  if constexpr (GMODE == 0) {
    if (tid < 128) s_tok[tid] = src[m0 + tid];
  }
  __syncthreads();

  f32x4v acc[4][4];
  #pragma unroll
  for (int i = 0; i < 4; ++i)
    #pragma unroll
    for (int j = 0; j < 4; ++j) {
      acc[i][j][0] = 0.f; acc[i][j][1] = 0.f; acc[i][j][2] = 0.f; acc[i][j][3] = 0.f;
    }

  int atok[4]; size_t abase[4];
  #pragma unroll
  for (int i = 0; i < 4; ++i) {
    const int lm = wr*64 + i*16 + lr;
    if constexpr (GMODE == 0) {
      const int tok = s_tok[lm];
      atok[i] = tok;
      abase[i] = (size_t)tok * K;
    } else {
      atok[i] = m0 + lm;
      abase[i] = 0;
    }
  }
  const half8 zero8 = {};

  for (int k0 = 0; k0 < K; k0 += 32) {
    const int kk = k0 + lg*8;
    half8 afr[4], bfr[4];
    #pragma unroll
    for (int i = 0; i < 4; ++i) {
      if constexpr (GMODE == 0) {
        afr[i] = *(const half8*)((const _Float16*)embh + abase[i] + kk);
        if (atok[i] == 0) afr[i] = zero8;
      } else {
        const int m = atok[i];
        const _Float16* p = (kk < 512)
            ? ((const _Float16*)Af + (size_t)m * rsF + kk)
            : ((const _Float16*)Ab + (size_t)m * rsB + (kk - 512));
        afr[i] = *(const half8*)p;
      }
    }
    #pragma unroll
    for (int j = 0; j < 4; ++j) {
      const int n = n0 + wc*64 + j*16 + lr;
      bfr[j] = *(const half8*)((const _Float16*)Wh + (size_t)n * K + kk);
    }
    #pragma unroll
    for (int i = 0; i < 4; ++i)
      #pragma unroll
      for (int j = 0; j < 4; ++j)
        acc[i][j] = __builtin_amdgcn_mfma_f32_16x16x32_f16(afr[i], bfr[j], acc[i][j], 0, 0, 0);
  }

  if constexpr (EPI == 0) {
    #pragma unroll
    for (int i = 0; i < 4; ++i) {
      #pragma unroll
      for (int j = 0; j < 4; ++j) {
        const int n = n0 + wc*64 + j*16 + lr;
        #pragma unroll
        for (int r = 0; r < 4; ++r) {
          const int m = m0 + wr*64 + i*16 + lg*4 + r;
          Cx[(size_t)m * N + n] = __float2half(acc[i][j][r]);
        }
      }
    }
  } else {
    #pragma unroll
    for (int j = 0; j < 4; ++j) {
      const int n = n0 + wc*64 + j*16 + lr;
      const float bj = bias[n];
      #pragma unroll
      for (int i = 0; i < 4; ++i) {
        #pragma unroll
        for (int r = 0; r < 4; ++r) {
          const int m = m0 + wr*64 + i*16 + lg*4 + r;
          Cf[(size_t)m * N + n] = tanhf(acc[i][j][r] + bj);
        }
      }
    }
  }
}

// -------- in-place LayerNorm per 512-chunk (3 gates) + gain/bias fold -------
template<typename XT>
__global__ __launch_bounds__(256)
void ln3_kernel(XT* __restrict__ xp, const float* __restrict__ g,
                const float* __restrict__ be, const float* __restrict__ b)
{
  const size_t base = (size_t)blockIdx.x * G3_;
  const int t = threadIdx.x;
  float v[6];
  #pragma unroll
  for (int gg = 0; gg < 3; ++gg) {
    v[gg*2+0] = toF(xp[base + gg*512 + t]);
    v[gg*2+1] = toF(xp[base + gg*512 + 256 + t]);
  }
  float s0 = v[0]+v[1], q0 = v[0]*v[0]+v[1]*v[1];
  float s1 = v[2]+v[3], q1 = v[2]*v[2]+v[3]*v[3];
  float s2 = v[4]+v[5], q2 = v[4]*v[4]+v[5]*v[5];
  #pragma unroll
  for (int m = 1; m < 64; m <<= 1) {
    s0 += __shfl_xor(s0, m); q0 += __shfl_xor(q0, m);
    s1 += __shfl_xor(s1, m); q1 += __shfl_xor(q1, m);
    s2 += __shfl_xor(s2, m); q2 += __shfl_xor(q2, m);
  }
  __shared__ float red[4][6];
  __shared__ float stat[6];
  const int wid = t >> 6, lane = t & 63;
  if (lane == 0) { red[wid][0]=s0; red[wid][1]=q0; red[wid][2]=s1; red[wid][3]=q1; red[wid][4]=s2; red[wid][5]=q2; }
  __syncthreads();
  if (t < 6) stat[t] = red[0][t] + red[1][t] + red[2][t] + red[3][t];
  __syncthreads();
  #pragma unroll
  for (int gg = 0; gg < 3; ++gg) {
    const float mu  = stat[gg*2]   * (1.f/512.f);
    const float var = stat[gg*2+1] * (1.f/512.f) - mu*mu;
    const float sc  = rsqrtf(var + 1e-5f);
    #pragma unroll
    for (int u = 0; u < 2; ++u) {
      const int c = gg*512 + u*256 + t;
      storeF(&xp[base + c], (v[gg*2+u] - mu) * sc * g[c] + be[c] + b[c]);
    }
  }
}

// --------------------------- persistent scan kernel -------------------------
// (unchanged from round 8 — measured-best sync protocol)
template<typename XT, typename HT>
__global__ __launch_bounds__(256, 2)
void scan_kernel(const XT* __restrict__ xp_f, const XT* __restrict__ xp_b,
                 const float* __restrict__ Whh_f, const float* __restrict__ Whh_b,
                 const float* __restrict__ gf, const float* __restrict__ bef, const float* __restrict__ bfv,
                 const float* __restrict__ gbv, const float* __restrict__ beb, const float* __restrict__ bbv,
                 float* __restrict__ hbuf, float* __restrict__ part,
                 unsigned* __restrict__ flags,
                 HT* __restrict__ houtF, int rsF, XT* __restrict__ houtB, int rsB,
                 float* __restrict__ outhid, int dirbase)
{
  __shared__ float hT[8][512];
  __shared__ float red[4][16][26];
  __shared__ float statL[48];
  __shared__ int sdead;

  const int bid  = blockIdx.x;
  const int gidx = dirbase*8 + (bid >> 5);
  const int dir  = gidx >> 3;
  const int bg   = gidx & 7;
  const int js   = bid & 31;
  const int tid  = threadIdx.x;
  const int jloc = tid & 15;
  const int pb   = tid >> 4;
  const int wid  = tid >> 6;
  const int ksw  = (tid >> 4) & 3;
  const int j    = js*16 + jloc;

  const XT* xp   = dir ? xp_b : xp_f;
  const float* W = dir ? Whh_b : Whh_f;
  const float* gv  = dir ? gbv : gf;
  const float* bev = dir ? beb : bef;
  const float* bv  = dir ? bbv : bfv;
  float* h = hbuf + dir * (B_ * H_);
  float* pgrp = part + (size_t)gidx * (48*32);
  unsigned* hfl = flags + (size_t)gidx * 2048;
  unsigned* sfl = hfl + 1024;

  if (tid == 0) sdead = 0;

  float w[3][32];
  {
    #pragma unroll
    for (int r = 0; r < 3; ++r) {
      const float* wr = W + (size_t)(r*H_ + j) * H_ + pb * 32;
      #pragma unroll
      for (int c = 0; c < 8; ++c) {
        const int p = (c + ksw*2) & 7;
        float4 f = *(const float4*)(wr + p*4);
        w[r][c*4+0] = f.x; w[r][c*4+1] = f.y; w[r][c*4+2] = f.z; w[r][c*4+3] = f.w;
      }
    }
  }
  const float gr0 = gv[j],            gr1 = gv[H_+j],               gr2 = gv[2*H_+j];
  const float gb0 = bev[j] + bv[j],   gb1 = bev[H_+j] + bv[H_+j],   gb2 = bev[2*H_+j] + bv[2*H_+j];
  __syncthreads();

  for (int t = 0; t < S_; ++t) {
    const int tf = dir ? (S_ - 1 - t) : t;
    float xr = 0.f, xz = 0.f, xn = 0.f;
    if (pb < 8) {
      const size_t xbase = ((size_t)tf * B_ + bg*8 + pb) * G3_;
      xr = toF(xp[xbase + j]);
      xz = toF(xp[xbase + H_ + j]);
      xn = toF(xp[xbase + 2*H_ + j]);
    }

    if (tid < 32 && !sdead) {
      const unsigned tgt = (unsigned)t;
      int guard = 0;
      while (flagLoad(&hfl[tid*32]) < tgt) {
        __builtin_amdgcn_s_sleep(1);
        if (++guard > (1 << 22)) { sdead = 1; break; }
      }
    }
    __syncthreads();

    {
      const int row = tid >> 5;
      const int seg = tid & 31;
      const ULL* hr = (const ULL*)(h + (size_t)(bg*8 + row) * H_);
      ULL v[8];
      #pragma unroll
      for (int i = 0; i < 8; ++i) v[i] = cohLoad8(hr + seg + i*32);
      ULL* dst = (ULL*)&hT[row][0];
      #pragma unroll
      for (int i = 0; i < 8; ++i) dst[seg + i*32] = v[i];
    }
    __syncthreads();

    for (int b = 0; b < 8; ++b) {
      float a0 = 0.f, a1 = 0.f, a2 = 0.f;
      #pragma unroll
      for (int c = 0; c < 8; ++c) {
        const int p = (c + ksw*2) & 7;
        const float4 hv = *(const float4*)&hT[b][pb*32 + p*4];
        a0 += hv.x*w[0][c*4+0] + hv.y*w[0][c*4+1] + hv.z*w[0][c*4+2] + hv.w*w[0][c*4+3];
        a1 += hv.x*w[1][c*4+0] + hv.y*w[1][c*4+1] + hv.z*w[1][c*4+2] + hv.w*w[1][c*4+3];
        a2 += hv.x*w[2][c*4+0] + hv.y*w[2][c*4+1] + hv.z*w[2][c*4+2] + hv.w*w[2][c*4+3];
      }
      a0 += __shfl_xor(a0, 16); a0 += __shfl_xor(a0, 32);
      a1 += __shfl_xor(a1, 16); a1 += __shfl_xor(a1, 32);
      a2 += __shfl_xor(a2, 16); a2 += __shfl_xor(a2, 32);
      if (ksw == 0) {
        red[wid][jloc][b*3+0] = a0; red[wid][jloc][b*3+1] = a1; red[wid][jloc][b*3+2] = a2;
      }
    }
    __syncthreads();

    float vr = 0.f, vz = 0.f, vn = 0.f;
    if (pb < 8) {
      vr = red[0][jloc][pb*3+0]+red[1][jloc][pb*3+0]+red[2][jloc][pb*3+0]+red[3][jloc][pb*3+0];
      vz = red[0][jloc][pb*3+1]+red[1][jloc][pb*3+1]+red[2][jloc][pb*3+1]+red[3][jloc][pb*3+1];
      vn = red[0][jloc][pb*3+2]+red[1][jloc][pb*3+2]+red[2][jloc][pb*3+2]+red[3][jloc][pb*3+2];

      float sr = vr, qr = vr*vr, sz = vz, qz = vz*vz, sn = vn, qn = vn*vn;
      #pragma unroll
      for (int m = 1; m < 16; m <<= 1) {
        sr += __shfl_xor(sr, m); qr += __shfl_xor(qr, m);
        sz += __shfl_xor(sz, m); qz += __shfl_xor(qz, m);
        sn += __shfl_xor(sn, m); qn += __shfl_xor(qn, m);
      }
      if (jloc == 0) {
        cohStore4(&pgrp[(pb*6+0)*32 + js], sr);
        cohStore4(&pgrp[(pb*6+1)*32 + js], qr);
        cohStore4(&pgrp[(pb*6+2)*32 + js], sz);
        cohStore4(&pgrp[(pb*6+3)*32 + js], qz);
        cohStore4(&pgrp[(pb*6+4)*32 + js], sn);
        cohStore4(&pgrp[(pb*6+5)*32 + js], qn);
      }
    }
    asm volatile("s_waitcnt vmcnt(0)" ::: "memory");
    __syncthreads();

    if (tid == 0) flagStore(&sfl[js*32], (unsigned)(t + 1));
    if (tid < 32 && !sdead) {
      const unsigned tgt = (unsigned)(t + 1);
      int guard = 0;
      while (flagLoad(&sfl[tid*32]) < tgt) {
        __builtin_amdgcn_s_sleep(1);
        if (++guard > (1 << 22)) { sdead = 1; break; }
      }
    }
    __syncthreads();

    if (tid < 48) {
      const ULL* prow = (const ULL*)(pgrp + tid * 32);
      float s = 0.f;
      #pragma unroll
      for (int u = 0; u < 16; ++u) {
        ULL v = cohLoad8(prow + u);
        union { ULL u64; float f[2]; } cv; cv.u64 = v;
        s += cv.f[0] + cv.f[1];
      }
      statL[tid] = s;
    }
    __syncthreads();

    if (pb < 8) {
      const int ab = bg*8 + pb;
      const float mur   = statL[pb*6+0]*(1.f/512.f);
      const float var_r = statL[pb*6+1]*(1.f/512.f) - mur*mur;
      const float muz   = statL[pb*6+2]*(1.f/512.f);
      const float var_z = statL[pb*6+3]*(1.f/512.f) - muz*muz;
      const float mun   = statL[pb*6+4]*(1.f/512.f);
      const float var_n = statL[pb*6+5]*(1.f/512.f) - mun*mun;
      const float hr_ = (vr - mur) * rsqrtf(var_r + 1e-5f) * gr0 + gb0;
      const float hz_ = (vz - muz) * rsqrtf(var_z + 1e-5f) * gr1 + gb1;
      const float hn_ = (vn - mun) * rsqrtf(var_n + 1e-5f) * gr2 + gb2;
      const float rg = 1.f / (1.f + __expf(-(xr + hr_)));
      const float zg = 1.f / (1.f + __expf(-(xz + hz_)));
      const float ng = tanhf(xn + rg * hn_);
      const float hprev = hT[pb][j];
      const float hnew = (1.f - zg) * ng + zg * hprev;
      cohStore4(&h[(size_t)ab * H_ + j], hnew);
      if (dir == 0) storeF(&houtF[((size_t)tf * B_ + ab) * rsF + j], hnew);
      else          storeF(&houtB[((size_t)tf * B_ + ab) * rsB + j], hnew);
      if (t == S_ - 1) outhid[((size_t)dir * B_ + ab) * H_ + j] = hnew;
    }
    asm volatile("s_waitcnt vmcnt(0)" ::: "memory");
    __syncthreads();
    if (tid == 0) flagStore(&hfl[js*32], (unsigned)(t + 1));
  }
}

// --------------------------------- host side --------------------------------
// ctrl: hbuf 256KB | part 96KB | flags 128KB | pad -> 512KB
static const size_t kCtrlBytes = 524288;
static const size_t kXpElems = (size_t)S_ * B_ * G3_;   // 100,663,296
static const size_t kHElems  = (size_t)S_ * B_ * H_;    //  33,554,432
static const size_t kEmbElems  = (size_t)V_ * E_;       //  16,384,000
static const size_t kWihElems  = (size_t)G3_ * E_;      //     786,432
static const size_t kWoutElems = (size_t)H_ * 2 * H_;   //     524,288

struct Args {
  const int* src; const float* emb;
  const float *Wih_f, *Whh_f, *bih_f, *bhh_f, *gih_f, *beih_f, *ghh_f, *behh_f;
  const float *Wih_b, *Whh_b, *bih_b, *bhh_b, *gih_b, *beih_b, *ghh_b, *behh_b;
  const float *Wout, *bout;
  float* out; void* ws; hipStream_t stream;
};

// parallel: both directions concurrent; all big intermediates fp16; MFMA GEMMs.
static void run_parallel(const Args& a)
{
  float* hbuf = (float*)a.ws;
  float* part = hbuf + 65536;
  unsigned* flags = (unsigned*)(part + 24576);
  f16* xpf = (f16*)((char*)a.ws + kCtrlBytes);
  f16* xpb = xpf + kXpElems;
  f16* emb16 = xpb + kXpElems;
  f16* w16f = emb16 + kEmbElems;
  f16* w16b = w16f + kWihElems;
  f16* wout16 = w16b + kWihElems;
  float* outhid = a.out + kHElems;

  hipMemsetAsync(a.ws, 0, kCtrlBytes, a.stream);

  convF2H<<<dim3(1024), dim3(256), 0, a.stream>>>(a.emb, emb16, (long)kEmbElems);
  convF2H<<<dim3(256), dim3(256), 0, a.stream>>>(a.Wih_f, w16f, (long)kWihElems);
  convF2H<<<dim3(256), dim3(256), 0, a.stream>>>(a.Wih_b, w16b, (long)kWihElems);
  convF2H<<<dim3(256), dim3(256), 0, a.stream>>>(a.Wout, wout16, (long)kWoutElems);

  gemm16<0,0><<<dim3(512,12), dim3(256), 0, a.stream>>>(
      a.src, emb16, (const f16*)nullptr, 0, (const f16*)nullptr, 0,
      w16f, xpf, nullptr, nullptr, G3_, E_);
  gemm16<0,0><<<dim3(512,12), dim3(256), 0, a.stream>>>(
      a.src, emb16, (const f16*)nullptr, 0, (const f16*)nullptr, 0,
      w16b, xpb, nullptr, nullptr, G3_, E_);
  ln3_kernel<f16><<<dim3(S_*B_), dim3(256), 0, a.stream>>>(xpf, a.gih_f, a.beih_f, a.bih_f);
  ln3_kernel<f16><<<dim3(S_*B_), dim3(256), 0, a.stream>>>(xpb, a.gih_b, a.beih_b, a.bih_b);

  scan_kernel<f16,f16><<<dim3(512), dim3(256), 0, a.stream>>>(
      xpf, xpb, a.Whh_f, a.Whh_b, a.ghh_f, a.behh_f, a.bhh_f,
      a.ghh_b, a.behh_b, a.bhh_b, hbuf, part, flags,
      xpf, G3_, xpb, G3_, outhid, 0);

  gemm16<1,1><<<dim3(512,4), dim3(256), 0, a.stream>>>(
      nullptr, nullptr, xpf, G3_, xpb, G3_,
      wout16, nullptr, a.out, a.bout, H_, 2*H_);
}

// sequential fallback (smaller ws): one xp buffer; yf -> hf, yb -> xp cols 0..511.
static void run_sequential(const Args& a)
{
  float* hbuf = (float*)a.ws;
  float* part = hbuf + 65536;
  unsigned* flags = (unsigned*)(part + 24576);
  f16* xp = (f16*)((char*)a.ws + kCtrlBytes);
  f16* hf = xp + kXpElems;
  f16* emb16 = hf + kHElems;
  f16* w16f = emb16 + kEmbElems;
  f16* w16b = w16f + kWihElems;
  f16* wout16 = w16b + kWihElems;
  float* outhid = a.out + kHElems;

  hipMemsetAsync(a.ws, 0, kCtrlBytes, a.stream);

  convF2H<<<dim3(1024), dim3(256), 0, a.stream>>>(a.emb, emb16, (long)kEmbElems);
  convF2H<<<dim3(256), dim3(256), 0, a.stream>>>(a.Wih_f, w16f, (long)kWihElems);
  convF2H<<<dim3(256), dim3(256), 0, a.stream>>>(a.Wih_b, w16b, (long)kWihElems);
  convF2H<<<dim3(256), dim3(256), 0, a.stream>>>(a.Wout, wout16, (long)kWoutElems);

  gemm16<0,0><<<dim3(512,12), dim3(256), 0, a.stream>>>(
      a.src, emb16, (const f16*)nullptr, 0, (const f16*)nullptr, 0,
      w16f, xp, nullptr, nullptr, G3_, E_);
  ln3_kernel<f16><<<dim3(S_*B_), dim3(256), 0, a.stream>>>(xp, a.gih_f, a.beih_f, a.bih_f);
  scan_kernel<f16,f16><<<dim3(256), dim3(256), 0, a.stream>>>(
      xp, xp, a.Whh_f, a.Whh_b, a.ghh_f, a.behh_f, a.bhh_f,
      a.ghh_b, a.behh_b, a.bhh_b, hbuf, part, flags,
      hf, H_, xp, G3_, outhid, 0);

  gemm16<0,0><<<dim3(512,12), dim3(256), 0, a.stream>>>(
      a.src, emb16, (const f16*)nullptr, 0, (const f16*)nullptr, 0,
      w16b, xp, nullptr, nullptr, G3_, E_);
  ln3_kernel<f16><<<dim3(S_*B_), dim3(256), 0, a.stream>>>(xp, a.gih_b, a.beih_b, a.bih_b);
  scan_kernel<f16,f16><<<dim3(256), dim3(256), 0, a.stream>>>(
      xp, xp, a.Whh_f, a.Whh_b, a.ghh_f, a.behh_f, a.bhh_f,
      a.ghh_b, a.behh_b, a.bhh_b, hbuf, part, flags,
      hf, H_, xp, G3_, outhid, 1);

  gemm16<1,1><<<dim3(512,4), dim3(256), 0, a.stream>>>(
      nullptr, nullptr, hf, H_, xp, G3_,
      wout16, nullptr, a.out, a.bout, H_, 2*H_);
}

extern "C" void kernel_launch(void* const* d_in, const int* in_sizes, int n_in,
                              void* d_out, int out_size, void* d_ws, size_t ws_size,
                              hipStream_t stream)
{
  Args a;
  a.src    = (const int*)  d_in[0];
  a.emb    = (const float*)d_in[1];
  a.Wih_f  = (const float*)d_in[2];
  a.Whh_f  = (const float*)d_in[3];
  a.bih_f  = (const float*)d_in[4];
  a.bhh_f  = (const float*)d_in[5];
  a.gih_f  = (const float*)d_in[6];
  a.beih_f = (const float*)d_in[7];
  a.ghh_f  = (const float*)d_in[8];
  a.behh_f = (const float*)d_in[9];
  a.Wih_b  = (const float*)d_in[10];
  a.Whh_b  = (const float*)d_in[11];
  a.bih_b  = (const float*)d_in[12];
  a.bhh_b  = (const float*)d_in[13];
  a.gih_b  = (const float*)d_in[14];
  a.beih_b = (const float*)d_in[15];
  a.ghh_b  = (const float*)d_in[16];
  a.behh_b = (const float*)d_in[17];
  a.Wout   = (const float*)d_in[18];
  a.bout   = (const float*)d_in[19];
  a.out = (float*)d_out;
  a.ws = d_ws;
  a.stream = stream;

  int dev = 0, cus = 0;
  hipGetDevice(&dev);
  hipDeviceGetAttribute(&cus, hipDeviceAttributeMultiprocessorCount, dev);

  const size_t extraElems = kEmbElems + 2*kWihElems + kWoutElems;
  const size_t needP = kCtrlBytes + (2*kXpElems + extraElems) * 2;          // ~420 MB
  const size_t needS = kCtrlBytes + (kXpElems + kHElems + extraElems) * 2;  // ~293 MB

  const bool sane = (n_in == 20) && (in_sizes[0] == S_*B_) && (in_sizes[1] == V_*E_)
                 && (in_sizes[3] == G3_*H_) && (in_sizes[18] == H_*2*H_);

  float sigv = 0.f;
  bool ran = false;
  if (!sane) {
    sigv = 20000.f + (float)n_in;
  } else if (cus < 256) {
    sigv = 100000.f + (float)cus;
  } else if (ws_size >= needP) { run_parallel(a);   ran = true; }
  else if (ws_size >= needS)   { run_sequential(a); ran = true; }
  else {
    unsigned wsMB = (unsigned)(ws_size >> 20);
    if (wsMB > 998) wsMB = 998;
    sigv = 1000.f + (float)wsMB;
  }

  if (!ran) {
    signal_kernel<<<dim3(1024), dim3(256), 0, stream>>>(a.out, (long)out_size, sigv);
  } else {
    hipError_t e = hipGetLastError();
    if (e != hipSuccess) {
      signal_kernel<<<dim3(1024), dim3(256), 0, stream>>>(a.out, (long)out_size,
                                                          10000.f + (float)(int)e);
    }
  }
}

// Round 12
// 10832.902 us; speedup vs baseline: 1.0008x; 1.0008x over previous
//
#include <hip/hip_runtime.h>
#include <hip/hip_bf16.h>
#include <hip/hip_fp16.h>

#define S_ 1024
#define B_ 64
#define E_ 512
#define H_ 512
#define G3_ 1536
#define V_ 32000

typedef __hip_bfloat16 bf16;
typedef __half f16;
typedef unsigned long long ULL;

typedef _Float16 half8 __attribute__((ext_vector_type(8)));
typedef float f32x4v __attribute__((ext_vector_type(4)));

// ---------- dtype helpers ----------
template<typename T> struct alignas(4*sizeof(T)) V4 { T v[4]; };

__device__ __forceinline__ float toF(float x){ return x; }
__device__ __forceinline__ float toF(bf16 x){ return __bfloat162float(x); }
__device__ __forceinline__ float toF(f16 x){ return __half2float(x); }
__device__ __forceinline__ void storeF(float* p, float v){ *p = v; }
__device__ __forceinline__ void storeF(bf16* p, float v){ *p = __float2bfloat16(v); }
__device__ __forceinline__ void storeF(f16* p, float v){ *p = __float2half(v); }

__device__ __forceinline__ ULL cohLoad8(const ULL* p){
  return __hip_atomic_load(p, __ATOMIC_RELAXED, __HIP_MEMORY_SCOPE_AGENT);
}
__device__ __forceinline__ void cohStore4(float* p, float v){
  __hip_atomic_store(p, v, __ATOMIC_RELAXED, __HIP_MEMORY_SCOPE_AGENT);
}
__device__ __forceinline__ unsigned flagLoad(const unsigned* p){
  return __hip_atomic_load(p, __ATOMIC_RELAXED, __HIP_MEMORY_SCOPE_AGENT);
}
__device__ __forceinline__ void flagStore(unsigned* p, unsigned v){
  __hip_atomic_store(p, v, __ATOMIC_RELAXED, __HIP_MEMORY_SCOPE_AGENT);
}

// ------------------------------ signal kernel -------------------------------
__global__ __launch_bounds__(256)
void signal_kernel(float* __restrict__ out, long n, float v)
{
  long i = (long)blockIdx.x * 256 + threadIdx.x;
  const long stride = (long)gridDim.x * 256;
  for (; i < n; i += stride) out[i] = v;
}

// ---------------------------- fp32 -> fp16 convert --------------------------
__global__ __launch_bounds__(256)
void convF2H(const float* __restrict__ in, f16* __restrict__ out, long n)
{
  long i = ((long)blockIdx.x * 256 + threadIdx.x) * 8;
  const long stride = (long)gridDim.x * 256 * 8;
  for (; i < n; i += stride) {
    float4 a = *(const float4*)(in + i);
    float4 b = *(const float4*)(in + i + 4);
    half8 o;
    o[0] = (_Float16)a.x; o[1] = (_Float16)a.y; o[2] = (_Float16)a.z; o[3] = (_Float16)a.w;
    o[4] = (_Float16)b.x; o[5] = (_Float16)b.y; o[6] = (_Float16)b.z; o[7] = (_Float16)b.w;
    *(half8*)((_Float16*)out + i) = o;
  }
}

// ------------------------- MFMA fp16 GEMM (no LDS) ---------------------------
// C[m][n] = sum_k A[m][k] * W[n][k], A/W fp16, fp32 accumulate.
// Block 128x128, 4 waves (2x2), wave tile 64x64 = 4x4 MFMA 16x16x32 tiles.
// A/B fragments: lane l loads 8 contiguous fp16 at k = k0 + (l>>4)*8 from
// row (l&15) of its sub-tile. Same per-lane k-slot bijection for A and B =>
// layout-correct independent of the HW k-group map. C/D: col=l&15,
// row=(l>>4)*4+reg [HW-verified].
// GMODE 0: A row = emb16[src[m]] * (src!=0)    (gather, K=512)
// GMODE 1: A[m][k] = k<512 ? Af[m*rsF+k] : Ab[m*rsB+k-512]
// EPI 0: store f16 to Cx (row stride N). EPI 1: f32 tanh(acc+bias[n]) to Cf.
template<int GMODE, int EPI>
__global__ __launch_bounds__(256)
void gemm16(const int* __restrict__ src, const f16* __restrict__ embh,
            const f16* __restrict__ Af, int rsF,
            const f16* __restrict__ Ab, int rsB,
            const f16* __restrict__ Wh,
            f16* __restrict__ Cx, float* __restrict__ Cf,
            const float* __restrict__ bias, int N, int K)
{
  __shared__ int s_tok[128];
  const int tid = threadIdx.x;
  const int m0 = blockIdx.x * 128;
  const int n0 = blockIdx.y * 128;
  const int wid = tid >> 6, lane = tid & 63;
  const int wr = wid >> 1, wc = wid & 1;
  const int lr = lane & 15, lg = lane >> 4;

  if constexpr (GMODE == 0) {
    if (tid < 128) s_tok[tid] = src[m0 + tid];
  }
  __syncthreads();

  f32x4v acc[4][4];
  #pragma unroll
  for (int i = 0; i < 4; ++i)
    #pragma unroll
    for (int j = 0; j < 4; ++j) {
      acc[i][j][0] = 0.f; acc[i][j][1] = 0.f; acc[i][j][2] = 0.f; acc[i][j][3] = 0.f;
    }

  int atok[4]; size_t abase[4];
  #pragma unroll
  for (int i = 0; i < 4; ++i) {
    const int lm = wr*64 + i*16 + lr;
    if constexpr (GMODE == 0) {
      const int tok = s_tok[lm];
      atok[i] = tok;
      abase[i] = (size_t)tok * K;
    } else {
      atok[i] = m0 + lm;
      abase[i] = 0;
    }
  }
  const half8 zero8 = {};

  for (int k0 = 0; k0 < K; k0 += 32) {
    const int kk = k0 + lg*8;
    half8 afr[4], bfr[4];
    #pragma unroll
    for (int i = 0; i < 4; ++i) {
      if constexpr (GMODE == 0) {
        afr[i] = *(const half8*)((const _Float16*)embh + abase[i] + kk);
        if (atok[i] == 0) afr[i] = zero8;
      } else {
        const int m = atok[i];
        const _Float16* p = (kk < 512)
            ? ((const _Float16*)Af + (size_t)m * rsF + kk)
            : ((const _Float16*)Ab + (size_t)m * rsB + (kk - 512));
        afr[i] = *(const half8*)p;
      }
    }
    #pragma unroll
    for (int j = 0; j < 4; ++j) {
      const int n = n0 + wc*64 + j*16 + lr;
      bfr[j] = *(const half8*)((const _Float16*)Wh + (size_t)n * K + kk);
    }
    #pragma unroll
    for (int i = 0; i < 4; ++i)
      #pragma unroll
      for (int j = 0; j < 4; ++j)
        acc[i][j] = __builtin_amdgcn_mfma_f32_16x16x32_f16(afr[i], bfr[j], acc[i][j], 0, 0, 0);
  }

  if constexpr (EPI == 0) {
    #pragma unroll
    for (int i = 0; i < 4; ++i) {
      #pragma unroll
      for (int j = 0; j < 4; ++j) {
        const int n = n0 + wc*64 + j*16 + lr;
        #pragma unroll
        for (int r = 0; r < 4; ++r) {
          const int m = m0 + wr*64 + i*16 + lg*4 + r;
          Cx[(size_t)m * N + n] = __float2half(acc[i][j][r]);
        }
      }
    }
  } else {
    #pragma unroll
    for (int j = 0; j < 4; ++j) {
      const int n = n0 + wc*64 + j*16 + lr;
      const float bj = bias[n];
      #pragma unroll
      for (int i = 0; i < 4; ++i) {
        #pragma unroll
        for (int r = 0; r < 4; ++r) {
          const int m = m0 + wr*64 + i*16 + lg*4 + r;
          Cf[(size_t)m * N + n] = tanhf(acc[i][j][r] + bj);
        }
      }
    }
  }
}

// -------- in-place LayerNorm per 512-chunk (3 gates) + gain/bias fold -------
template<typename XT>
__global__ __launch_bounds__(256)
void ln3_kernel(XT* __restrict__ xp, const float* __restrict__ g,
                const float* __restrict__ be, const float* __restrict__ b)
{
  const size_t base = (size_t)blockIdx.x * G3_;
  const int t = threadIdx.x;
  float v[6];
  #pragma unroll
  for (int gg = 0; gg < 3; ++gg) {
    v[gg*2+0] = toF(xp[base + gg*512 + t]);
    v[gg*2+1] = toF(xp[base + gg*512 + 256 + t]);
  }
  float s0 = v[0]+v[1], q0 = v[0]*v[0]+v[1]*v[1];
  float s1 = v[2]+v[3], q1 = v[2]*v[2]+v[3]*v[3];
  float s2 = v[4]+v[5], q2 = v[4]*v[4]+v[5]*v[5];
  #pragma unroll
  for (int m = 1; m < 64; m <<= 1) {
    s0 += __shfl_xor(s0, m); q0 += __shfl_xor(q0, m);
    s1 += __shfl_xor(s1, m); q1 += __shfl_xor(q1, m);
    s2 += __shfl_xor(s2, m); q2 += __shfl_xor(q2, m);
  }
  __shared__ float red[4][6];
  __shared__ float stat[6];
  const int wid = t >> 6, lane = t & 63;
  if (lane == 0) { red[wid][0]=s0; red[wid][1]=q0; red[wid][2]=s1; red[wid][3]=q1; red[wid][4]=s2; red[wid][5]=q2; }
  __syncthreads();
  if (t < 6) stat[t] = red[0][t] + red[1][t] + red[2][t] + red[3][t];
  __syncthreads();
  #pragma unroll
  for (int gg = 0; gg < 3; ++gg) {
    const float mu  = stat[gg*2]   * (1.f/512.f);
    const float var = stat[gg*2+1] * (1.f/512.f) - mu*mu;
    const float sc  = rsqrtf(var + 1e-5f);
    #pragma unroll
    for (int u = 0; u < 2; ++u) {
      const int c = gg*512 + u*256 + t;
      storeF(&xp[base + c], (v[gg*2+u] - mu) * sc * g[c] + be[c] + b[c]);
    }
  }
}

// --------------------------- persistent scan kernel -------------------------
// (unchanged from round 8 — measured-best sync protocol)
template<typename XT, typename HT>
__global__ __launch_bounds__(256, 2)
void scan_kernel(const XT* __restrict__ xp_f, const XT* __restrict__ xp_b,
                 const float* __restrict__ Whh_f, const float* __restrict__ Whh_b,
                 const float* __restrict__ gf, const float* __restrict__ bef, const float* __restrict__ bfv,
                 const float* __restrict__ gbv, const float* __restrict__ beb, const float* __restrict__ bbv,
                 float* __restrict__ hbuf, float* __restrict__ part,
                 unsigned* __restrict__ flags,
                 HT* __restrict__ houtF, int rsF, XT* __restrict__ houtB, int rsB,
                 float* __restrict__ outhid, int dirbase)
{
  __shared__ float hT[8][512];
  __shared__ float red[4][16][26];
  __shared__ float statL[48];
  __shared__ int sdead;

  const int bid  = blockIdx.x;
  const int gidx = dirbase*8 + (bid >> 5);
  const int dir  = gidx >> 3;
  const int bg   = gidx & 7;
  const int js   = bid & 31;
  const int tid  = threadIdx.x;
  const int jloc = tid & 15;
  const int pb   = tid >> 4;
  const int wid  = tid >> 6;
  const int ksw  = (tid >> 4) & 3;
  const int j    = js*16 + jloc;

  const XT* xp   = dir ? xp_b : xp_f;
  const float* W = dir ? Whh_b : Whh_f;
  const float* gv  = dir ? gbv : gf;
  const float* bev = dir ? beb : bef;
  const float* bv  = dir ? bbv : bfv;
  float* h = hbuf + dir * (B_ * H_);
  float* pgrp = part + (size_t)gidx * (48*32);
  unsigned* hfl = flags + (size_t)gidx * 2048;
  unsigned* sfl = hfl + 1024;

  if (tid == 0) sdead = 0;

  float w[3][32];
  {
    #pragma unroll
    for (int r = 0; r < 3; ++r) {
      const float* wr = W + (size_t)(r*H_ + j) * H_ + pb * 32;
      #pragma unroll
      for (int c = 0; c < 8; ++c) {
        const int p = (c + ksw*2) & 7;
        float4 f = *(const float4*)(wr + p*4);
        w[r][c*4+0] = f.x; w[r][c*4+1] = f.y; w[r][c*4+2] = f.z; w[r][c*4+3] = f.w;
      }
    }
  }
  const float gr0 = gv[j],            gr1 = gv[H_+j],               gr2 = gv[2*H_+j];
  const float gb0 = bev[j] + bv[j],   gb1 = bev[H_+j] + bv[H_+j],   gb2 = bev[2*H_+j] + bv[2*H_+j];
  __syncthreads();

  for (int t = 0; t < S_; ++t) {
    const int tf = dir ? (S_ - 1 - t) : t;
    float xr = 0.f, xz = 0.f, xn = 0.f;
    if (pb < 8) {
      const size_t xbase = ((size_t)tf * B_ + bg*8 + pb) * G3_;
      xr = toF(xp[xbase + j]);
      xz = toF(xp[xbase + H_ + j]);
      xn = toF(xp[xbase + 2*H_ + j]);
    }

    if (tid < 32 && !sdead) {
      const unsigned tgt = (unsigned)t;
      int guard = 0;
      while (flagLoad(&hfl[tid*32]) < tgt) {
        __builtin_amdgcn_s_sleep(1);
        if (++guard > (1 << 22)) { sdead = 1; break; }
      }
    }
    __syncthreads();

    {
      const int row = tid >> 5;
      const int seg = tid & 31;
      const ULL* hr = (const ULL*)(h + (size_t)(bg*8 + row) * H_);
      ULL v[8];
      #pragma unroll
      for (int i = 0; i < 8; ++i) v[i] = cohLoad8(hr + seg + i*32);
      ULL* dst = (ULL*)&hT[row][0];
      #pragma unroll
      for (int i = 0; i < 8; ++i) dst[seg + i*32] = v[i];
    }
    __syncthreads();

    for (int b = 0; b < 8; ++b) {
      float a0 = 0.f, a1 = 0.f, a2 = 0.f;
      #pragma unroll
      for (int c = 0; c < 8; ++c) {
        const int p = (c + ksw*2) & 7;
        const float4 hv = *(const float4*)&hT[b][pb*32 + p*4];
        a0 += hv.x*w[0][c*4+0] + hv.y*w[0][c*4+1] + hv.z*w[0][c*4+2] + hv.w*w[0][c*4+3];
        a1 += hv.x*w[1][c*4+0] + hv.y*w[1][c*4+1] + hv.z*w[1][c*4+2] + hv.w*w[1][c*4+3];
        a2 += hv.x*w[2][c*4+0] + hv.y*w[2][c*4+1] + hv.z*w[2][c*4+2] + hv.w*w[2][c*4+3];
      }
      a0 += __shfl_xor(a0, 16); a0 += __shfl_xor(a0, 32);
      a1 += __shfl_xor(a1, 16); a1 += __shfl_xor(a1, 32);
      a2 += __shfl_xor(a2, 16); a2 += __shfl_xor(a2, 32);
      if (ksw == 0) {
        red[wid][jloc][b*3+0] = a0; red[wid][jloc][b*3+1] = a1; red[wid][jloc][b*3+2] = a2;
      }
    }
    __syncthreads();

    float vr = 0.f, vz = 0.f, vn = 0.f;
    if (pb < 8) {
      vr = red[0][jloc][pb*3+0]+red[1][jloc][pb*3+0]+red[2][jloc][pb*3+0]+red[3][jloc][pb*3+0];
      vz = red[0][jloc][pb*3+1]+red[1][jloc][pb*3+1]+red[2][jloc][pb*3+1]+red[3][jloc][pb*3+1];
      vn = red[0][jloc][pb*3+2]+red[1][jloc][pb*3+2]+red[2][jloc][pb*3+2]+red[3][jloc][pb*3+2];

      float sr = vr, qr = vr*vr, sz = vz, qz = vz*vz, sn = vn, qn = vn*vn;
      #pragma unroll
      for (int m = 1; m < 16; m <<= 1) {
        sr += __shfl_xor(sr, m); qr += __shfl_xor(qr, m);
        sz += __shfl_xor(sz, m); qz += __shfl_xor(qz, m);
        sn += __shfl_xor(sn, m); qn += __shfl_xor(qn, m);
      }
      if (jloc == 0) {
        cohStore4(&pgrp[(pb*6+0)*32 + js], sr);
        cohStore4(&pgrp[(pb*6+1)*32 + js], qr);
        cohStore4(&pgrp[(pb*6+2)*32 + js], sz);
        cohStore4(&pgrp[(pb*6+3)*32 + js], qz);
        cohStore4(&pgrp[(pb*6+4)*32 + js], sn);
        cohStore4(&pgrp[(pb*6+5)*32 + js], qn);
      }
    }
    asm volatile("s_waitcnt vmcnt(0)" ::: "memory");
    __syncthreads();

    if (tid == 0) flagStore(&sfl[js*32], (unsigned)(t + 1));
    if (tid < 32 && !sdead) {
      const unsigned tgt = (unsigned)(t + 1);
      int guard = 0;
      while (flagLoad(&sfl[tid*32]) < tgt) {
        __builtin_amdgcn_s_sleep(1);
        if (++guard > (1 << 22)) { sdead = 1; break; }
      }
    }
    __syncthreads();

    if (tid < 48) {
      const ULL* prow = (const ULL*)(pgrp + tid * 32);
      float s = 0.f;
      #pragma unroll
      for (int u = 0; u < 16; ++u) {
        ULL v = cohLoad8(prow + u);
        union { ULL u64; float f[2]; } cv; cv.u64 = v;
        s += cv.f[0] + cv.f[1];
      }
      statL[tid] = s;
    }
    __syncthreads();

    if (pb < 8) {
      const int ab = bg*8 + pb;
      const float mur   = statL[pb*6+0]*(1.f/512.f);
      const float var_r = statL[pb*6+1]*(1.f/512.f) - mur*mur;
      const float muz   = statL[pb*6+2]*(1.f/512.f);
      const float var_z = statL[pb*6+3]*(1.f/512.f) - muz*muz;
      const float mun   = statL[pb*6+4]*(1.f/512.f);
      const float var_n = statL[pb*6+5]*(1.f/512.f) - mun*mun;
      const float hr_ = (vr - mur) * rsqrtf(var_r + 1e-5f) * gr0 + gb0;
      const float hz_ = (vz - muz) * rsqrtf(var_z + 1e-5f) * gr1 + gb1;
      const float hn_ = (vn - mun) * rsqrtf(var_n + 1e-5f) * gr2 + gb2;
      const float rg = 1.f / (1.f + __expf(-(xr + hr_)));
      const float zg = 1.f / (1.f + __expf(-(xz + hz_)));
      const float ng = tanhf(xn + rg * hn_);
      const float hprev = hT[pb][j];
      const float hnew = (1.f - zg) * ng + zg * hprev;
      cohStore4(&h[(size_t)ab * H_ + j], hnew);
      if (dir == 0) storeF(&houtF[((size_t)tf * B_ + ab) * rsF + j], hnew);
      else          storeF(&houtB[((size_t)tf * B_ + ab) * rsB + j], hnew);
      if (t == S_ - 1) outhid[((size_t)dir * B_ + ab) * H_ + j] = hnew;
    }
    asm volatile("s_waitcnt vmcnt(0)" ::: "memory");
    __syncthreads();
    if (tid == 0) flagStore(&hfl[js*32], (unsigned)(t + 1));
  }
}

// --------------------------------- host side --------------------------------
// ctrl: hbuf 256KB | part 96KB | flags 128KB | pad -> 512KB
static const size_t kCtrlBytes = 524288;
static const size_t kXpElems = (size_t)S_ * B_ * G3_;   // 100,663,296
static const size_t kHElems  = (size_t)S_ * B_ * H_;    //  33,554,432
static const size_t kEmbElems  = (size_t)V_ * E_;       //  16,384,000
static const size_t kWihElems  = (size_t)G3_ * E_;      //     786,432
static const size_t kWoutElems = (size_t)H_ * 2 * H_;   //     524,288

struct Args {
  const int* src; const float* emb;
  const float *Wih_f, *Whh_f, *bih_f, *bhh_f, *gih_f, *beih_f, *ghh_f, *behh_f;
  const float *Wih_b, *Whh_b, *bih_b, *bhh_b, *gih_b, *beih_b, *ghh_b, *behh_b;
  const float *Wout, *bout;
  float* out; void* ws; hipStream_t stream;
};

// parallel: both directions concurrent; all big intermediates fp16; MFMA GEMMs.
static void run_parallel(const Args& a)
{
  float* hbuf = (float*)a.ws;
  float* part = hbuf + 65536;
  unsigned* flags = (unsigned*)(part + 24576);
  f16* xpf = (f16*)((char*)a.ws + kCtrlBytes);
  f16* xpb = xpf + kXpElems;
  f16* emb16 = xpb + kXpElems;
  f16* w16f = emb16 + kEmbElems;
  f16* w16b = w16f + kWihElems;
  f16* wout16 = w16b + kWihElems;
  float* outhid = a.out + kHElems;

  hipMemsetAsync(a.ws, 0, kCtrlBytes, a.stream);

  convF2H<<<dim3(1024), dim3(256), 0, a.stream>>>(a.emb, emb16, (long)kEmbElems);
  convF2H<<<dim3(256), dim3(256), 0, a.stream>>>(a.Wih_f, w16f, (long)kWihElems);
  convF2H<<<dim3(256), dim3(256), 0, a.stream>>>(a.Wih_b, w16b, (long)kWihElems);
  convF2H<<<dim3(256), dim3(256), 0, a.stream>>>(a.Wout, wout16, (long)kWoutElems);

  gemm16<0,0><<<dim3(512,12), dim3(256), 0, a.stream>>>(
      a.src, emb16, (const f16*)nullptr, 0, (const f16*)nullptr, 0,
      w16f, xpf, nullptr, nullptr, G3_, E_);
  gemm16<0,0><<<dim3(512,12), dim3(256), 0, a.stream>>>(
      a.src, emb16, (const f16*)nullptr, 0, (const f16*)nullptr, 0,
      w16b, xpb, nullptr, nullptr, G3_, E_);
  ln3_kernel<f16><<<dim3(S_*B_), dim3(256), 0, a.stream>>>(xpf, a.gih_f, a.beih_f, a.bih_f);
  ln3_kernel<f16><<<dim3(S_*B_), dim3(256), 0, a.stream>>>(xpb, a.gih_b, a.beih_b, a.bih_b);

  scan_kernel<f16,f16><<<dim3(512), dim3(256), 0, a.stream>>>(
      xpf, xpb, a.Whh_f, a.Whh_b, a.ghh_f, a.behh_f, a.bhh_f,
      a.ghh_b, a.behh_b, a.bhh_b, hbuf, part, flags,
      xpf, G3_, xpb, G3_, outhid, 0);

  gemm16<1,1><<<dim3(512,4), dim3(256), 0, a.stream>>>(
      nullptr, nullptr, xpf, G3_, xpb, G3_,
      wout16, nullptr, a.out, a.bout, H_, 2*H_);
}

// sequential fallback (smaller ws): one xp buffer; yf -> hf, yb -> xp cols 0..511.
static void run_sequential(const Args& a)
{
  float* hbuf = (float*)a.ws;
  float* part = hbuf + 65536;
  unsigned* flags = (unsigned*)(part + 24576);
  f16* xp = (f16*)((char*)a.ws + kCtrlBytes);
  f16* hf = xp + kXpElems;
  f16* emb16 = hf + kHElems;
  f16* w16f = emb16 + kEmbElems;
  f16* w16b = w16f + kWihElems;
  f16* wout16 = w16b + kWihElems;
  float* outhid = a.out + kHElems;

  hipMemsetAsync(a.ws, 0, kCtrlBytes, a.stream);

  convF2H<<<dim3(1024), dim3(256), 0, a.stream>>>(a.emb, emb16, (long)kEmbElems);
  convF2H<<<dim3(256), dim3(256), 0, a.stream>>>(a.Wih_f, w16f, (long)kWihElems);
  convF2H<<<dim3(256), dim3(256), 0, a.stream>>>(a.Wih_b, w16b, (long)kWihElems);
  convF2H<<<dim3(256), dim3(256), 0, a.stream>>>(a.Wout, wout16, (long)kWoutElems);

  gemm16<0,0><<<dim3(512,12), dim3(256), 0, a.stream>>>(
      a.src, emb16, (const f16*)nullptr, 0, (const f16*)nullptr, 0,
      w16f, xp, nullptr, nullptr, G3_, E_);
  ln3_kernel<f16><<<dim3(S_*B_), dim3(256), 0, a.stream>>>(xp, a.gih_f, a.beih_f, a.bih_f);
  scan_kernel<f16,f16><<<dim3(256), dim3(256), 0, a.stream>>>(
      xp, xp, a.Whh_f, a.Whh_b, a.ghh_f, a.behh_f, a.bhh_f,
      a.ghh_b, a.behh_b, a.bhh_b, hbuf, part, flags,
      hf, H_, xp, G3_, outhid, 0);

  gemm16<0,0><<<dim3(512,12), dim3(256), 0, a.stream>>>(
      a.src, emb16, (const f16*)nullptr, 0, (const f16*)nullptr, 0,
      w16b, xp, nullptr, nullptr, G3_, E_);
  ln3_kernel<f16><<<dim3(S_*B_), dim3(256), 0, a.stream>>>(xp, a.gih_b, a.beih_b, a.bih_b);
  scan_kernel<f16,f16><<<dim3(256), dim3(256), 0, a.stream>>>(
      xp, xp, a.Whh_f, a.Whh_b, a.ghh_f, a.behh_f, a.bhh_f,
      a.ghh_b, a.behh_b, a.bhh_b, hbuf, part, flags,
      hf, H_, xp, G3_, outhid, 1);

  gemm16<1,1><<<dim3(512,4), dim3(256), 0, a.stream>>>(
      nullptr, nullptr, hf, H_, xp, G3_,
      wout16, nullptr, a.out, a.bout, H_, 2*H_);
}

extern "C" void kernel_launch(void* const* d_in, const int* in_sizes, int n_in,
                              void* d_out, int out_size, void* d_ws, size_t ws_size,
                              hipStream_t stream)
{
  Args a;
  a.src    = (const int*)  d_in[0];
  a.emb    = (const float*)d_in[1];
  a.Wih_f  = (const float*)d_in[2];
  a.Whh_f  = (const float*)d_in[3];
  a.bih_f  = (const float*)d_in[4];
  a.bhh_f  = (const float*)d_in[5];
  a.gih_f  = (const float*)d_in[6];
  a.beih_f = (const float*)d_in[7];
  a.ghh_f  = (const float*)d_in[8];
  a.behh_f = (const float*)d_in[9];
  a.Wih_b  = (const float*)d_in[10];
  a.Whh_b  = (const float*)d_in[11];
  a.bih_b  = (const float*)d_in[12];
  a.bhh_b  = (const float*)d_in[13];
  a.gih_b  = (const float*)d_in[14];
  a.beih_b = (const float*)d_in[15];
  a.ghh_b  = (const float*)d_in[16];
  a.behh_b = (const float*)d_in[17];
  a.Wout   = (const float*)d_in[18];
  a.bout   = (const float*)d_in[19];
  a.out = (float*)d_out;
  a.ws = d_ws;
  a.stream = stream;

  int dev = 0, cus = 0;
  hipGetDevice(&dev);
  hipDeviceGetAttribute(&cus, hipDeviceAttributeMultiprocessorCount, dev);

  const size_t extraElems = kEmbElems + 2*kWihElems + kWoutElems;
  const size_t needP = kCtrlBytes + (2*kXpElems + extraElems) * 2;          // ~420 MB
  const size_t needS = kCtrlBytes + (kXpElems + kHElems + extraElems) * 2;  // ~293 MB

  const bool sane = (n_in == 20) && (in_sizes[0] == S_*B_) && (in_sizes[1] == V_*E_)
                 && (in_sizes[3] == G3_*H_) && (in_sizes[18] == H_*2*H_);

  float sigv = 0.f;
  bool ran = false;
  if (!sane) {
    sigv = 20000.f + (float)n_in;
  } else if (cus < 256) {
    sigv = 100000.f + (float)cus;
  } else if (ws_size >= needP) { run_parallel(a);   ran = true; }
  else if (ws_size >= needS)   { run_sequential(a); ran = true; }
  else {
    unsigned wsMB = (unsigned)(ws_size >> 20);
    if (wsMB > 998) wsMB = 998;
    sigv = 1000.f + (float)wsMB;
  }

  if (!ran) {
    signal_kernel<<<dim3(1024), dim3(256), 0, stream>>>(a.out, (long)out_size, sigv);
  } else {
    hipError_t e = hipGetLastError();
    if (e != hipSuccess) {
      signal_kernel<<<dim3(1024), dim3(256), 0, stream>>>(a.out, (long)out_size,
                                                          10000.f + (float)(int)e);
    }
  }
}